// Round 1
// baseline (1020.293 us; speedup 1.0000x reference)
//
#include <hip/hip_runtime.h>
#include <hip/hip_bf16.h>
#include <stdint.h>

#define TOKENS  4096
#define D_MODEL 4096
#define D_FF    16384
#define K_SEL   4096

typedef __attribute__((ext_vector_type(8))) short short8;
typedef __attribute__((ext_vector_type(4))) float float4v;

typedef const __attribute__((address_space(1))) unsigned int* gptr_t;
typedef __attribute__((address_space(3))) unsigned int* lptr_t;

// fp32 -> bf16 round-to-nearest-even
__device__ inline unsigned short f2bf(float f) {
    union { float f; unsigned int u; } v; v.f = f;
    unsigned int r = v.u + 0x7fffu + ((v.u >> 16) & 1u);
    return (unsigned short)(r >> 16);
}

// ---------------------------------------------------------------------------
// Prep kernel 1: cast (and optionally row-gather) fp32 [rows][cols] -> bf16.
// 8 elements per thread, float4 loads, 16B stores.
// ---------------------------------------------------------------------------
__global__ void gather_cast_kernel(const float* __restrict__ src,
                                   const int* __restrict__ idx,
                                   unsigned short* __restrict__ dst,
                                   int cols) {
    long e = ((long)blockIdx.x * blockDim.x + threadIdx.x) * 8;
    int row = (int)(e / cols);
    int col = (int)(e - (long)row * cols);
    long srow = idx ? (long)idx[row] : (long)row;
    const float4* s = (const float4*)(src + srow * cols + col);
    float4 a = s[0], b = s[1];
    short8 o;
    o[0] = (short)f2bf(a.x); o[1] = (short)f2bf(a.y);
    o[2] = (short)f2bf(a.z); o[3] = (short)f2bf(a.w);
    o[4] = (short)f2bf(b.x); o[5] = (short)f2bf(b.y);
    o[6] = (short)f2bf(b.z); o[7] = (short)f2bf(b.w);
    *(short8*)(dst + e) = o;
}

// ---------------------------------------------------------------------------
// Prep kernel 2: gathered transpose-cast. dst[n][k] = bf16(src[idx[k]][n]).
// 32x32 tiles via LDS (pad +1 to kill bank conflicts).
// ---------------------------------------------------------------------------
__global__ void gather_transpose_cast_kernel(const float* __restrict__ src,
                                             const int* __restrict__ idx,
                                             unsigned short* __restrict__ dst,
                                             int srcCols, int rows) {
    __shared__ float tile[32][33];
    int tx = threadIdx.x;   // 0..31
    int ty = threadIdx.y;   // 0..7
    int k0 = blockIdx.x * 32;
    int n0 = blockIdx.y * 32;
#pragma unroll
    for (int r = 0; r < 4; ++r) {
        int k = k0 + ty + r * 8;
        long sr = idx[k];
        tile[ty + r * 8][tx] = src[sr * srcCols + n0 + tx];
    }
    __syncthreads();
#pragma unroll
    for (int r = 0; r < 4; ++r) {
        int n = n0 + ty + r * 8;
        dst[(long)n * rows + k0 + tx] = f2bf(tile[tx][ty + r * 8]);
    }
}

// ---------------------------------------------------------------------------
// NT bf16 GEMM (m97 structure): C[M][N] = A[M][K] * B[N][K]^T (+bias, +relu)
// 128x128 block tile, 256 threads = 4 waves (2x2 of 64x64), BK=64.
// LDS chunk-major [q][m][8bf16]: global_load_lds-compatible (base+lane*16)
// and ds_read_b128 fragment reads land 2-way-conflict (free).
// MODE 0: fp32 out, bias[col].  MODE 1: bf16 out, relu, bias[bidx[col]].
// ---------------------------------------------------------------------------
template <int MODE>
__global__ __launch_bounds__(256)
void gemm_nt(const unsigned short* __restrict__ A,
             const unsigned short* __restrict__ B,
             const float* __restrict__ bias,
             const int* __restrict__ bidx,
             void* __restrict__ Cout,
             int M, int N, int K) {
    __shared__ __align__(16) unsigned short As[8 * 128 * 8]; // 16 KB
    __shared__ __align__(16) unsigned short Bs[8 * 128 * 8]; // 16 KB

    const int tid  = threadIdx.x;
    const int lane = tid & 63;
    const int wave = tid >> 6;
    const int wm = wave >> 1;   // 0..1
    const int wn = wave & 1;    // 0..1
    const int bm = blockIdx.y * 128;
    const int bn = blockIdx.x * 128;

    // Staging descriptors: chunk p covers (q = p>>7, m = p&127); 16B each.
    const unsigned short* aPtr[4];
    const unsigned short* bPtr[4];
    unsigned short* aLds[4];
    unsigned short* bLds[4];
#pragma unroll
    for (int i = 0; i < 4; ++i) {
        int p = i * 256 + tid;
        int q = p >> 7, m = p & 127;
        aPtr[i] = A + (long)(bm + m) * K + q * 8;
        bPtr[i] = B + (long)(bn + m) * K + q * 8;
        aLds[i] = &As[p * 8];
        bLds[i] = &Bs[p * 8];
    }

    float4v acc[4][4];
#pragma unroll
    for (int i = 0; i < 4; ++i)
#pragma unroll
        for (int j = 0; j < 4; ++j)
            acc[i][j] = (float4v)(0.f);

    const int quad = lane >> 4;
    const int lr   = lane & 15;

    for (int k0 = 0; k0 < K; k0 += 64) {
#pragma unroll
        for (int i = 0; i < 4; ++i)
            __builtin_amdgcn_global_load_lds((gptr_t)(aPtr[i] + k0),
                                             (lptr_t)aLds[i], 16, 0, 0);
#pragma unroll
        for (int i = 0; i < 4; ++i)
            __builtin_amdgcn_global_load_lds((gptr_t)(bPtr[i] + k0),
                                             (lptr_t)bLds[i], 16, 0, 0);
        __syncthreads();

#pragma unroll
        for (int kk = 0; kk < 2; ++kk) {  // two 32-wide k-steps
            short8 af[4], bf[4];
            int q = kk * 4 + quad;
#pragma unroll
            for (int i = 0; i < 4; ++i) {
                int m = wm * 64 + i * 16 + lr;
                af[i] = *(const short8*)&As[(q * 128 + m) * 8];
            }
#pragma unroll
            for (int j = 0; j < 4; ++j) {
                int n = wn * 64 + j * 16 + lr;
                bf[j] = *(const short8*)&Bs[(q * 128 + n) * 8];
            }
#pragma unroll
            for (int i = 0; i < 4; ++i)
#pragma unroll
                for (int j = 0; j < 4; ++j)
                    acc[i][j] = __builtin_amdgcn_mfma_f32_16x16x32_bf16(
                        af[i], bf[j], acc[i][j], 0, 0, 0);
        }
        __syncthreads();
    }

    // Epilogue
#pragma unroll
    for (int i = 0; i < 4; ++i) {
        int rowBase = bm + wm * 64 + i * 16 + quad * 4;
#pragma unroll
        for (int j = 0; j < 4; ++j) {
            int col = bn + wn * 64 + j * 16 + lr;
            float bv = (MODE == 1) ? bias[bidx[col]] : bias[col];
#pragma unroll
            for (int r = 0; r < 4; ++r) {
                float v = acc[i][j][r] + bv;
                long off = (long)(rowBase + r) * N + col;
                if (MODE == 1) {
                    v = v > 0.f ? v : 0.f;
                    ((unsigned short*)Cout)[off] = f2bf(v);
                } else {
                    ((float*)Cout)[off] = v;
                }
            }
        }
    }
}

extern "C" void kernel_launch(void* const* d_in, const int* in_sizes, int n_in,
                              void* d_out, int out_size, void* d_ws, size_t ws_size,
                              hipStream_t stream) {
    const float* x      = (const float*)d_in[0];
    const float* fc1_w  = (const float*)d_in[1];
    const float* bias1  = (const float*)d_in[2];
    const float* fc2_wt = (const float*)d_in[3];
    const float* bias2  = (const float*)d_in[4];
    const int*   idx    = (const int*)d_in[5];

    char* ws = (char*)d_ws;
    unsigned short* Xb   = (unsigned short*)(ws);                         // 32 MB
    unsigned short* W1g  = (unsigned short*)(ws + ((size_t)32 << 20));    // 32 MB
    unsigned short* W2gT = (unsigned short*)(ws + ((size_t)64 << 20));    // 32 MB
    unsigned short* H    = (unsigned short*)(ws + ((size_t)96 << 20));    // 32 MB

    // 1) cast x -> bf16
    gather_cast_kernel<<<(TOKENS * D_MODEL / 8) / 256, 256, 0, stream>>>(
        x, nullptr, Xb, D_MODEL);
    // 2) gather fc1 rows -> bf16 W1g[k][d]
    gather_cast_kernel<<<(K_SEL * D_MODEL / 8) / 256, 256, 0, stream>>>(
        fc1_w, idx, W1g, D_MODEL);
    // 3) gather + transpose fc2 rows -> bf16 W2gT[n][k]
    gather_transpose_cast_kernel<<<dim3(K_SEL / 32, D_MODEL / 32), dim3(32, 8), 0, stream>>>(
        fc2_wt, idx, W2gT, D_MODEL, K_SEL);
    // 4) H = relu(Xb * W1g^T + bias1[idx])   [TOKENS x K_SEL] bf16
    gemm_nt<1><<<dim3(K_SEL / 128, TOKENS / 128), 256, 0, stream>>>(
        Xb, W1g, bias1, idx, (void*)H, TOKENS, K_SEL, D_MODEL);
    // 5) out = H * W2gT^T + bias2            [TOKENS x D_MODEL] fp32
    gemm_nt<0><<<dim3(D_MODEL / 128, TOKENS / 128), 256, 0, stream>>>(
        H, W2gT, bias2, nullptr, d_out, TOKENS, D_MODEL, K_SEL);
}